// Round 1
// baseline (33576.477 us; speedup 1.0000x reference)
//
#include <hip/hip_runtime.h>

#define B_ 64
#define S_ 512
#define I_ 1024
#define H_ 1024
#define G_ 4096  // 4*H

// ---------------------------------------------------------------------------
// x-projection GEMM: xp[M=B*S][4H] = X[M][I] * W_ih^T + (b_ih + b_hh)
// BM=128 BN=128 BK=16, 256 threads, per-thread 8x8 (rows contiguous, cols
// strided by 16 so LDS B-reads are conflict-free scalars and stores coalesce).
// ---------------------------------------------------------------------------
__global__ __launch_bounds__(256) void xproj_gemm(
    const float* __restrict__ X, const float* __restrict__ W,
    const float* __restrict__ bih, const float* __restrict__ bhh,
    float* __restrict__ out)
{
    __shared__ float As[16][132];  // [k][m], pad 132 keeps float4 alignment
    __shared__ float Bs[16][132];  // [k][n]

    const int tid = threadIdx.x;
    const int tx = tid & 15;   // col group: cols tx + 16*j
    const int ty = tid >> 4;   // row group: rows ty*8 + i
    const int m0 = blockIdx.y * 128;
    const int n0 = blockIdx.x * 128;

    const int lr = tid >> 2;          // 0..63
    const int lc = (tid & 3) << 2;    // 0,4,8,12

    float acc[8][8];
#pragma unroll
    for (int i = 0; i < 8; ++i)
#pragma unroll
        for (int j = 0; j < 8; ++j) acc[i][j] = 0.f;

    for (int k0 = 0; k0 < I_; k0 += 16) {
#pragma unroll
        for (int l = 0; l < 2; ++l) {
            int r = lr + 64 * l;
            float4 v = *(const float4*)(X + (size_t)(m0 + r) * I_ + k0 + lc);
            As[lc + 0][r] = v.x; As[lc + 1][r] = v.y;
            As[lc + 2][r] = v.z; As[lc + 3][r] = v.w;
            float4 w = *(const float4*)(W + (size_t)(n0 + r) * I_ + k0 + lc);
            Bs[lc + 0][r] = w.x; Bs[lc + 1][r] = w.y;
            Bs[lc + 2][r] = w.z; Bs[lc + 3][r] = w.w;
        }
        __syncthreads();
#pragma unroll
        for (int k = 0; k < 16; ++k) {
            float ar[8], br[8];
            *(float4*)&ar[0] = *(const float4*)&As[k][ty * 8];
            *(float4*)&ar[4] = *(const float4*)&As[k][ty * 8 + 4];
#pragma unroll
            for (int j = 0; j < 8; ++j) br[j] = Bs[k][tx + 16 * j];
#pragma unroll
            for (int i = 0; i < 8; ++i)
#pragma unroll
                for (int j = 0; j < 8; ++j)
                    acc[i][j] = fmaf(ar[i], br[j], acc[i][j]);
        }
        __syncthreads();
    }

    float bsum[8];
#pragma unroll
    for (int j = 0; j < 8; ++j) {
        int col = n0 + tx + 16 * j;
        bsum[j] = bih[col] + bhh[col];
    }
#pragma unroll
    for (int i = 0; i < 8; ++i) {
        size_t row = (size_t)(m0 + ty * 8 + i);
        float* orow = out + row * G_ + n0;
#pragma unroll
        for (int j = 0; j < 8; ++j)
            orow[tx + 16 * j] = acc[i][j] + bsum[j];
    }
}

// ---------------------------------------------------------------------------
// One LSTM timestep, fused: gates = xp_t + h_prev @ W_hh^T; elementwise;
// writes h_seq[:, s, :], updates c in place, writes h_next (ping-pong).
// grid = 256 blocks: blockIdx = colBlock(0..127)*2 + bhalf.
// Block tile: 32 batch rows x 8 h-cols (= 32 W_hh rows across the 4 gates).
// ---------------------------------------------------------------------------
__global__ __launch_bounds__(256) void lstm_step(
    const float* __restrict__ Whh, const float* __restrict__ xp,
    const float* __restrict__ hprev, float* __restrict__ hnext,
    float* __restrict__ cbuf, float* __restrict__ hseq,
    float* __restrict__ hlast, float* __restrict__ clast,
    int s, int isLast)
{
    __shared__ float Hs[32][68];  // [b][k] k-contig, stride 68 (16B aligned)
    __shared__ float Ws[32][65];  // [row][k] stride 65 -> conflict-free b32
    __shared__ float gsm[32][36]; // [b][row] gate exchange

    const int tid = threadIdx.x;
    const int tx = tid & 31;   // W-row index within block: g = tx>>3, c = tx&7
    const int ty = tid >> 5;   // 0..7 -> 4 batch rows each
    const int colBlock = blockIdx.x >> 1;
    const int bhalf = blockIdx.x & 1;
    const int col0 = colBlock * 8;
    const int bbase = bhalf * 32;

    const int g = tx >> 3, c = tx & 7;
    const int wrow = g * H_ + col0 + c;

    float acc[4] = {0.f, 0.f, 0.f, 0.f};

    for (int k0 = 0; k0 < H_; k0 += 64) {
#pragma unroll
        for (int l = 0; l < 2; ++l) {
            int idx = tid + 256 * l;
            int rr = idx >> 4;            // 0..31
            int kq = (idx & 15) << 2;     // 0..60
            int g2 = rr >> 3, cc = rr & 7;
            float4 w4 = *(const float4*)(Whh + (size_t)(g2 * H_ + col0 + cc) * H_ + k0 + kq);
            Ws[rr][kq + 0] = w4.x; Ws[rr][kq + 1] = w4.y;
            Ws[rr][kq + 2] = w4.z; Ws[rr][kq + 3] = w4.w;
            float4 h4 = *(const float4*)(hprev + (size_t)(bbase + rr) * H_ + k0 + kq);
            *(float4*)&Hs[rr][kq] = h4;
        }
        __syncthreads();
#pragma unroll
        for (int k = 0; k < 64; k += 4) {
            float b0 = Ws[tx][k + 0];
            float b1 = Ws[tx][k + 1];
            float b2 = Ws[tx][k + 2];
            float b3 = Ws[tx][k + 3];
#pragma unroll
            for (int i = 0; i < 4; ++i) {
                float4 a = *(const float4*)&Hs[ty * 4 + i][k];
                acc[i] = fmaf(a.x, b0, acc[i]);
                acc[i] = fmaf(a.y, b1, acc[i]);
                acc[i] = fmaf(a.z, b2, acc[i]);
                acc[i] = fmaf(a.w, b3, acc[i]);
            }
        }
        __syncthreads();
    }

    // add x-projection (includes both biases), exchange gates via LDS
#pragma unroll
    for (int i = 0; i < 4; ++i) {
        int bg = bbase + ty * 4 + i;
        gsm[ty * 4 + i][tx] = acc[i] + xp[((size_t)bg * S_ + s) * G_ + wrow];
    }
    __syncthreads();

    {
        int bl = tid >> 3;  // 0..31
        int cc = tid & 7;   // 0..7
        int bg = bbase + bl;
        int col = col0 + cc;
        float gi = gsm[bl][0 * 8 + cc];
        float gf = gsm[bl][1 * 8 + cc];
        float gg = gsm[bl][2 * 8 + cc];
        float go = gsm[bl][3 * 8 + cc];
        float ii = 1.f / (1.f + expf(-gi));
        float ff = 1.f / (1.f + expf(-gf));
        float g2 = tanhf(gg);
        float oo = 1.f / (1.f + expf(-go));
        size_t cidx = (size_t)bg * H_ + col;
        float cp = cbuf[cidx];
        float cn = ff * cp + ii * g2;
        float hn = oo * tanhf(cn);
        cbuf[cidx] = cn;
        hnext[cidx] = hn;
        hseq[((size_t)bg * S_ + s) * H_ + col] = hn;
        if (isLast) {
            hlast[cidx] = hn;
            clast[cidx] = cn;
        }
    }
}

extern "C" void kernel_launch(void* const* d_in, const int* in_sizes, int n_in,
                              void* d_out, int out_size, void* d_ws, size_t ws_size,
                              hipStream_t stream) {
    const float* x   = (const float*)d_in[0];
    const float* Wih = (const float*)d_in[1];
    const float* Whh = (const float*)d_in[2];
    const float* bih = (const float*)d_in[3];
    const float* bhh = (const float*)d_in[4];
    float* out = (float*)d_out;
    float* ws  = (float*)d_ws;

    // workspace layout (floats)
    float* xp = ws;                          // 32768*4096 = 134217728
    float* h0 = ws + 134217728;              // 65536
    float* h1 = h0 + 65536;                  // 65536
    float* cb = h1 + 65536;                  // 65536

    float* hseq  = out;                              // 33554432
    float* hlast = out + (size_t)B_ * S_ * H_;       // 65536
    float* clast = hlast + (size_t)B_ * H_;          // 65536

    hipMemsetAsync(h0, 0, (size_t)B_ * H_ * sizeof(float), stream);
    hipMemsetAsync(cb, 0, (size_t)B_ * H_ * sizeof(float), stream);

    dim3 gg(G_ / 128, (B_ * S_) / 128);
    xproj_gemm<<<gg, 256, 0, stream>>>(x, Wih, bih, bhh, xp);

    for (int s = 0; s < S_; ++s) {
        const float* hp = (s & 1) ? h1 : h0;
        float* hn       = (s & 1) ? h0 : h1;
        lstm_step<<<256, 256, 0, stream>>>(Whh, xp, hp, hn, cb, hseq,
                                           hlast, clast, s, (s == S_ - 1) ? 1 : 0);
    }
}

// Round 2
// 6162.517 us; speedup vs baseline: 5.4485x; 5.4485x over previous
//
#include <hip/hip_runtime.h>

#define B_ 64
#define S_ 512
#define I_ 1024
#define H_ 1024
#define G_ 4096  // 4*H

typedef __attribute__((ext_vector_type(4))) float f32x4;
typedef __attribute__((ext_vector_type(8))) short bf16x8;

static __device__ __forceinline__ ushort f2b(float f) {
    union { float f; unsigned u; } v; v.f = f;
    unsigned u = v.u;
    unsigned r = (u + 0x7fffu + ((u >> 16) & 1u)) >> 16;
    return (ushort)r;
}
static __device__ __forceinline__ float b2f(ushort b) {
    union { unsigned u; float f; } v; v.u = ((unsigned)b) << 16; return v.f;
}

// ---------------------------------------------------------------------------
// fp32 -> bf16 conversion, vectorized (float4 in, ushort4 out)
// ---------------------------------------------------------------------------
__global__ __launch_bounds__(256) void conv_f2b_kernel(
    const float* __restrict__ in, ushort* __restrict__ out, int n4)
{
    int i = blockIdx.x * blockDim.x + threadIdx.x;
    int stride = gridDim.x * blockDim.x;
    for (; i < n4; i += stride) {
        float4 v = ((const float4*)in)[i];
        ushort4 o;
        o.x = f2b(v.x); o.y = f2b(v.y); o.z = f2b(v.z); o.w = f2b(v.w);
        ((ushort4*)out)[i] = o;
    }
}

// ---------------------------------------------------------------------------
// x-projection GEMM (bf16 MFMA): xp[M=B*S][4H] = X[M][I] @ W_ih^T + (b_ih+b_hh)
// BM=BN=128, BK=32, 256 threads = 4 waves (2x2), each wave 64x64 (4x4 frags).
// LDS tiles padded to 40 (80B row stride -> 2-way bank alias = free).
// xp stored as bf16.
// ---------------------------------------------------------------------------
__global__ __launch_bounds__(256) void xproj_mfma(
    const ushort* __restrict__ Xb, const ushort* __restrict__ Wb,
    const float* __restrict__ bih, const float* __restrict__ bhh,
    ushort* __restrict__ xp)
{
    __shared__ ushort As[128][40];
    __shared__ ushort Bs[128][40];
    const int tid  = threadIdx.x;
    const int lane = tid & 63;
    const int w    = tid >> 6;
    const int wm   = (w >> 1) * 64, wn = (w & 1) * 64;
    const int m0   = blockIdx.y * 128, n0 = blockIdx.x * 128;

    const int srow   = tid >> 2;        // 0..63 (+64 for 2nd chunk)
    const int schunk = (tid & 3) * 8;   // k element offset (16B)

    const ushort* Xr0 = Xb + (size_t)(m0 + srow) * I_ + schunk;
    const ushort* Xr1 = Xb + (size_t)(m0 + srow + 64) * I_ + schunk;
    const ushort* Wr0 = Wb + (size_t)(n0 + srow) * I_ + schunk;
    const ushort* Wr1 = Wb + (size_t)(n0 + srow + 64) * I_ + schunk;

    f32x4 acc[4][4];
#pragma unroll
    for (int mi = 0; mi < 4; ++mi)
#pragma unroll
        for (int ni = 0; ni < 4; ++ni)
#pragma unroll
            for (int r = 0; r < 4; ++r) acc[mi][ni][r] = 0.f;

    bf16x8 ra0 = *(const bf16x8*)Xr0;
    bf16x8 ra1 = *(const bf16x8*)Xr1;
    bf16x8 rb0 = *(const bf16x8*)Wr0;
    bf16x8 rb1 = *(const bf16x8*)Wr1;

    const int arow = lane & 15;       // fragment row/col within 16
    const int akg  = (lane >> 4) * 8; // k-group offset

    for (int kt = 0; kt < 32; ++kt) {
        __syncthreads();
        *(bf16x8*)&As[srow][schunk]      = ra0;
        *(bf16x8*)&As[srow + 64][schunk] = ra1;
        *(bf16x8*)&Bs[srow][schunk]      = rb0;
        *(bf16x8*)&Bs[srow + 64][schunk] = rb1;
        __syncthreads();
        if (kt < 31) {
            int k0 = (kt + 1) * 32;
            ra0 = *(const bf16x8*)(Xr0 + k0);
            ra1 = *(const bf16x8*)(Xr1 + k0);
            rb0 = *(const bf16x8*)(Wr0 + k0);
            rb1 = *(const bf16x8*)(Wr1 + k0);
        }
        bf16x8 af[4], bfv[4];
#pragma unroll
        for (int mi = 0; mi < 4; ++mi)
            af[mi] = *(const bf16x8*)&As[wm + mi * 16 + arow][akg];
#pragma unroll
        for (int ni = 0; ni < 4; ++ni)
            bfv[ni] = *(const bf16x8*)&Bs[wn + ni * 16 + arow][akg];
#pragma unroll
        for (int mi = 0; mi < 4; ++mi)
#pragma unroll
            for (int ni = 0; ni < 4; ++ni)
                acc[mi][ni] = __builtin_amdgcn_mfma_f32_16x16x32_bf16(
                    af[mi], bfv[ni], acc[mi][ni], 0, 0, 0);
    }

    float bsum[4];
#pragma unroll
    for (int ni = 0; ni < 4; ++ni) {
        int col = n0 + wn + ni * 16 + (lane & 15);
        bsum[ni] = bih[col] + bhh[col];
    }
#pragma unroll
    for (int mi = 0; mi < 4; ++mi)
#pragma unroll
        for (int ni = 0; ni < 4; ++ni) {
            int col = n0 + wn + ni * 16 + (lane & 15);
#pragma unroll
            for (int r = 0; r < 4; ++r) {
                int row = m0 + wm + mi * 16 + (lane >> 4) * 4 + r;
                xp[(size_t)row * G_ + col] = f2b(acc[mi][ni][r] + bsum[ni]);
            }
        }
}

// ---------------------------------------------------------------------------
// One LSTM step via MFMA. grid=256 blocks, 256 threads (4 waves).
// Block covers 4 h-cols x 4 gates (16 N-cols); wave w does batch rows w*16..+16.
// A (h, bf16) and B (W_hh, bf16) read straight from L2-hot global, depth-2
// register prefetch, 32 MFMAs per wave. Epilogue fuses activations + c/h
// update + h_seq write.
// ---------------------------------------------------------------------------
__global__ __launch_bounds__(256) void lstm_step_mfma(
    const ushort* __restrict__ Whhb, const ushort* __restrict__ xp,
    const ushort* __restrict__ hin, ushort* __restrict__ hout,
    float* __restrict__ cbuf, float* __restrict__ hseq,
    float* __restrict__ hlast, float* __restrict__ clast,
    int s, int isLast)
{
    __shared__ float gsm[4][16][17];
    const int tid  = threadIdx.x;
    const int lane = tid & 63;
    const int w    = tid >> 6;
    const int c0   = blockIdx.x * 4;
    const int j    = lane & 15;
    const int nrow = (j >> 2) * H_ + c0 + (j & 3);       // W_hh row (gate-dim)
    const ushort* Brow = Whhb + (size_t)nrow * H_ + ((lane >> 4) * 8);
    const ushort* Arow = hin + (size_t)(w * 16 + j) * H_ + ((lane >> 4) * 8);

    // epilogue operand prefetch (independent of K loop -> issues early)
    const int eb = tid >> 2, eci = tid & 3, ecol = c0 + eci;
    const ushort* xprow = xp + ((size_t)eb * S_ + s) * G_ + ecol;
    const ushort xv0 = xprow[0];
    const ushort xv1 = xprow[H_];
    const ushort xv2 = xprow[2 * H_];
    const ushort xv3 = xprow[3 * H_];
    const float  cp  = cbuf[eb * H_ + ecol];

    f32x4 acc;
#pragma unroll
    for (int r = 0; r < 4; ++r) acc[r] = 0.f;

    bf16x8 a[3][4], b[3][4];
#pragma unroll
    for (int p = 0; p < 2; ++p)
#pragma unroll
        for (int u = 0; u < 4; ++u) {
            a[p][u] = *(const bf16x8*)(Arow + (p * 4 + u) * 32);
            b[p][u] = *(const bf16x8*)(Brow + (p * 4 + u) * 32);
        }
#pragma unroll
    for (int blk = 0; blk < 8; ++blk) {
        const int cur = blk % 3;
        const int nxt = (blk + 2) % 3;
        if (blk < 6) {
#pragma unroll
            for (int u = 0; u < 4; ++u) {
                a[nxt][u] = *(const bf16x8*)(Arow + ((blk + 2) * 4 + u) * 32);
                b[nxt][u] = *(const bf16x8*)(Brow + ((blk + 2) * 4 + u) * 32);
            }
        }
#pragma unroll
        for (int u = 0; u < 4; ++u)
            acc = __builtin_amdgcn_mfma_f32_16x16x32_bf16(a[cur][u], b[cur][u], acc, 0, 0, 0);
    }

#pragma unroll
    for (int r = 0; r < 4; ++r)
        gsm[w][(lane >> 4) * 4 + r][j] = acc[r];
    __syncthreads();

    float gi = gsm[eb >> 4][eb & 15][0 * 4 + eci] + b2f(xv0);
    float gf = gsm[eb >> 4][eb & 15][1 * 4 + eci] + b2f(xv1);
    float gg = gsm[eb >> 4][eb & 15][2 * 4 + eci] + b2f(xv2);
    float go = gsm[eb >> 4][eb & 15][3 * 4 + eci] + b2f(xv3);

    float ii = 1.f / (1.f + __expf(-gi));
    float ff = 1.f / (1.f + __expf(-gf));
    float gt = 1.f - 2.f / (__expf(2.f * gg) + 1.f);
    float oo = 1.f / (1.f + __expf(-go));
    float cn = ff * cp + ii * gt;
    float hn = oo * (1.f - 2.f / (__expf(2.f * cn) + 1.f));

    cbuf[eb * H_ + ecol] = cn;
    hout[eb * H_ + ecol] = f2b(hn);
    hseq[((size_t)eb * S_ + s) * H_ + ecol] = hn;
    if (isLast) {
        hlast[eb * H_ + ecol] = hn;
        clast[eb * H_ + ecol] = cn;
    }
}

extern "C" void kernel_launch(void* const* d_in, const int* in_sizes, int n_in,
                              void* d_out, int out_size, void* d_ws, size_t ws_size,
                              hipStream_t stream) {
    const float* x   = (const float*)d_in[0];
    const float* Wih = (const float*)d_in[1];
    const float* Whh = (const float*)d_in[2];
    const float* bih = (const float*)d_in[3];
    const float* bhh = (const float*)d_in[4];
    float* out = (float*)d_out;

    // workspace layout (ushort elements)
    ushort* xp   = (ushort*)d_ws;           // 134217728 elems (268 MB)
    ushort* xbf  = xp + 134217728;          // 33554432
    ushort* wihb = xbf + 33554432;          // 4194304
    ushort* whhb = wihb + 4194304;          // 4194304
    ushort* hb0  = whhb + 4194304;          // 65536
    ushort* hb1  = hb0 + 65536;             // 65536
    float*  cb   = (float*)(hb1 + 65536);   // 65536 floats

    float* hseq  = out;                            // [B,S,H]
    float* hlast = out + (size_t)B_ * S_ * H_;
    float* clast = hlast + (size_t)B_ * H_;

    hipMemsetAsync(hb0, 0, (size_t)B_ * H_ * sizeof(ushort), stream);
    hipMemsetAsync(cb, 0, (size_t)B_ * H_ * sizeof(float), stream);

    conv_f2b_kernel<<<2048, 256, 0, stream>>>(x, xbf, (B_ * S_ * I_) / 4);
    conv_f2b_kernel<<<1024, 256, 0, stream>>>(Wih, wihb, (G_ * I_) / 4);
    conv_f2b_kernel<<<1024, 256, 0, stream>>>(Whh, whhb, (G_ * H_) / 4);

    dim3 gg(G_ / 128, (B_ * S_) / 128);  // x = n-tiles (share B panel), y = m
    xproj_mfma<<<gg, 256, 0, stream>>>(xbf, wihb, bih, bhh, xp);

    for (int s = 0; s < S_; ++s) {
        const ushort* hp = (s & 1) ? hb1 : hb0;
        ushort* hn       = (s & 1) ? hb0 : hb1;
        lstm_step_mfma<<<256, 256, 0, stream>>>(whhb, xp, hp, hn, cb, hseq,
                                                hlast, clast, s, (s == S_ - 1) ? 1 : 0);
    }
}